// Round 3
// baseline (285.783 us; speedup 1.0000x reference)
//
#include <hip/hip_runtime.h>
#include <hip/hip_bf16.h>

#define C_IN   256
#define C_OUT  512
#define NFILT  4

#define BM  128
#define SAS 264   // LDS A-row stride in bf16 elems (256+8): conflict-free b128 reads/writes

typedef __attribute__((ext_vector_type(8))) short bf16x8;
typedef __attribute__((ext_vector_type(4))) float floatx4;
typedef __attribute__((ext_vector_type(4))) float f4v;   // native vec for nontemporal builtins

union Pack8 { uint4 u; __hip_bfloat16 h[8]; };

__global__ void zero_cnt_kernel(int* __restrict__ cnt) {
    if (threadIdx.x < NFILT) cnt[threadIdx.x] = 0;
}

__global__ void bucketize_kernel(const float* __restrict__ xyz,
                                 int* __restrict__ idxbuf,
                                 int* __restrict__ cnt, int P) {
    int pid = blockIdx.x * blockDim.x + threadIdx.x;
    if (pid >= P) return;
    float x = xyz[pid * 3 + 0];
    float y = xyz[pid * 3 + 1];
    float z = xyz[pid * 3 + 2];
    float r2 = __fadd_rn(__fadd_rn(__fmul_rn(x, x), __fmul_rn(y, y)), __fmul_rn(z, z));
    float r = sqrtf(r2);
    int filt;
    if (r < 1.0f)        filt = 0;
    else if (r < 1.5f)   filt = 1;
    else if (r < 2.0f)   filt = 2;
    else if (r < 100.0f) filt = 3;
    else                 filt = 0;   // argmax over all-false returns 0

    int lane = threadIdx.x & 63;
    for (int f = 0; f < NFILT; ++f) {
        unsigned long long mask = __ballot(filt == f);
        if (mask == 0ull) continue;
        int leader = __ffsll((unsigned long long)mask) - 1;
        int base = 0;
        if (lane == leader) base = atomicAdd(&cnt[f], __popcll(mask));
        base = __shfl(base, leader);
        if (filt == f) {
            int off = __popcll(mask & ((1ull << lane) - 1ull));
            idxbuf[f * P + base + off] = pid;
        }
    }
}

// w[f][o][c] fp32  ->  wbt[((f*32 + c/8)*512 + o)*8 + (c&7)] bf16
// so a b-frag load (o = 16 consecutive across lanes, fixed k-chunk) is coalesced.
__global__ void convert_w_kernel(const float* __restrict__ w,
                                 ushort* __restrict__ wbt) {
    int t = blockIdx.x * blockDim.x + threadIdx.x;   // 64K threads, 8 elems each
    int c8 = t & 31;           // C_IN/8 chunks
    int fo = t >> 5;           // f*C_OUT + o
    int f  = fo >> 9;
    int o  = fo & 511;
    const float* src = w + (size_t)fo * C_IN + c8 * 8;
    f4v v0 = *(const f4v*)(src + 0);
    f4v v1 = *(const f4v*)(src + 4);
    Pack8 p;
    p.h[0] = __float2bfloat16(v0.x); p.h[1] = __float2bfloat16(v0.y);
    p.h[2] = __float2bfloat16(v0.z); p.h[3] = __float2bfloat16(v0.w);
    p.h[4] = __float2bfloat16(v1.x); p.h[5] = __float2bfloat16(v1.y);
    p.h[6] = __float2bfloat16(v1.z); p.h[7] = __float2bfloat16(v1.w);
    *(uint4*)(wbt + ((size_t)(f * 32 + c8) * 512 + o) * 8) = p.u;
}

__global__ __launch_bounds__(256, 2) void gemm_kernel(
    const float* __restrict__ feat, const ushort* __restrict__ wbt,
    const float* __restrict__ bias, const int* __restrict__ idxbuf,
    const int* __restrict__ cnt, float* __restrict__ out, int P)
{
    __shared__ ushort sA[BM * SAS];
    __shared__ float  sBias[C_OUT];
    __shared__ int    sIdx[BM];

    // map linear block id -> (filter f, local row-tile lt)
    int t = blockIdx.x;
    int f = -1, lt = 0, cn = 0;
    for (int ff = 0; ff < NFILT; ++ff) {
        int c = cnt[ff];
        int nt = (c + BM - 1) / BM;
        if (t < nt) { f = ff; lt = t; cn = c; break; }
        t -= nt;
    }
    if (f < 0) return;

    int tid = threadIdx.x;
    int rowBase = lt * BM;
    if (tid < BM) {
        int r = rowBase + tid;
        sIdx[tid] = (r < cn) ? idxbuf[f * P + r] : -1;
    }
    sBias[tid]       = bias[f * C_OUT + tid];
    sBias[tid + 256] = bias[f * C_OUT + tid + 256];
    __syncthreads();

    // ---- stage A: 128 rows x 256 k, fp32 gathered -> bf16 LDS, once ----
    int sRow = tid >> 1, sHalf = tid & 1;
    int myIdx = sIdx[sRow];
    const float* aRow = feat + (size_t)(myIdx < 0 ? 0 : myIdx) * C_IN + sHalf * 16;
    ushort* dA = &sA[sRow * SAS + sHalf * 16];
#pragma unroll
    for (int it = 0; it < 8; ++it) {
        const float* ap = aRow + it * 32;
        f4v a0 = __builtin_nontemporal_load((const f4v*)(ap + 0));
        f4v a1 = __builtin_nontemporal_load((const f4v*)(ap + 4));
        f4v a2 = __builtin_nontemporal_load((const f4v*)(ap + 8));
        f4v a3 = __builtin_nontemporal_load((const f4v*)(ap + 12));
        Pack8 p0, p1;
        p0.h[0] = __float2bfloat16(a0.x); p0.h[1] = __float2bfloat16(a0.y);
        p0.h[2] = __float2bfloat16(a0.z); p0.h[3] = __float2bfloat16(a0.w);
        p0.h[4] = __float2bfloat16(a1.x); p0.h[5] = __float2bfloat16(a1.y);
        p0.h[6] = __float2bfloat16(a1.z); p0.h[7] = __float2bfloat16(a1.w);
        p1.h[0] = __float2bfloat16(a2.x); p1.h[1] = __float2bfloat16(a2.y);
        p1.h[2] = __float2bfloat16(a2.z); p1.h[3] = __float2bfloat16(a2.w);
        p1.h[4] = __float2bfloat16(a3.x); p1.h[5] = __float2bfloat16(a3.y);
        p1.h[6] = __float2bfloat16(a3.z); p1.h[7] = __float2bfloat16(a3.w);
        *(uint4*)(dA + it * 32 + 0) = p0.u;
        *(uint4*)(dA + it * 32 + 8) = p1.u;
    }
    __syncthreads();

    // ---- compute: wave = 32 rows x 128 cols per o-tile; loop 4 o-tiles ----
    int wid = tid >> 6, lane = tid & 63;
    int lcol = lane & 15, quad = lane >> 4;
    int rbase = wid * 32;
    int aOff0 = (rbase + lcol) * SAS + quad * 8;
    int aOff1 = aOff0 + 16 * SAS;

    int    pid_[2][4];
    size_t obase_[2][4];
#pragma unroll
    for (int i = 0; i < 2; ++i)
#pragma unroll
        for (int r = 0; r < 4; ++r) {
            int p_ = sIdx[rbase + i * 16 + quad * 4 + r];
            pid_[i][r]   = p_;
            obase_[i][r] = (size_t)(p_ < 0 ? 0 : p_) * C_OUT + lcol;
        }

    // per-lane base into transposed weights: (f, k-chunk=quad, o=lcol)
    const ushort* bQuad = wbt + ((size_t)(f * 32 + quad) * 512 + lcol) * 8;

    for (int ot = 0; ot < 4; ++ot) {
        floatx4 acc[2][8];
#pragma unroll
        for (int i = 0; i < 2; ++i)
#pragma unroll
            for (int j = 0; j < 8; ++j)
                acc[i][j] = (floatx4){0.f, 0.f, 0.f, 0.f};

        const ushort* bOt = bQuad + (size_t)ot * 128 * 8;

        bf16x8 af[2][2], bfr[2][8];
        af[0][0] = *(const bf16x8*)&sA[aOff0];
        af[0][1] = *(const bf16x8*)&sA[aOff1];
#pragma unroll
        for (int j = 0; j < 8; ++j)
            bfr[0][j] = *(const bf16x8*)(bOt + j * 16 * 8);

#pragma unroll
        for (int kk = 0; kk < 8; ++kk) {
            int cur = kk & 1, nxt = cur ^ 1;
            if (kk < 7) {
                af[nxt][0] = *(const bf16x8*)&sA[aOff0 + (kk + 1) * 32];
                af[nxt][1] = *(const bf16x8*)&sA[aOff1 + (kk + 1) * 32];
                const ushort* bp = bOt + (size_t)(kk + 1) * 4 * 512 * 8;
#pragma unroll
                for (int j = 0; j < 8; ++j)
                    bfr[nxt][j] = *(const bf16x8*)(bp + j * 16 * 8);
            }
#pragma unroll
            for (int i = 0; i < 2; ++i)
#pragma unroll
                for (int j = 0; j < 8; ++j)
                    acc[i][j] = __builtin_amdgcn_mfma_f32_16x16x32_bf16(
                        af[cur][i], bfr[cur][j], acc[i][j], 0, 0, 0);
        }

        // epilogue: scatter rows by point id, add bias, nontemporal stores
#pragma unroll
        for (int j = 0; j < 8; ++j) {
            float bv = sBias[ot * 128 + j * 16 + lcol];
#pragma unroll
            for (int i = 0; i < 2; ++i)
#pragma unroll
                for (int r = 0; r < 4; ++r) {
                    if (pid_[i][r] >= 0)
                        __builtin_nontemporal_store(acc[i][j][r] + bv,
                            out + obase_[i][r] + ot * 128 + j * 16);
                }
        }
    }
}

extern "C" void kernel_launch(void* const* d_in, const int* in_sizes, int n_in,
                              void* d_out, int out_size, void* d_ws, size_t ws_size,
                              hipStream_t stream) {
    const float* feat = (const float*)d_in[0];
    const float* xyz  = (const float*)d_in[1];
    const float* w    = (const float*)d_in[2];
    const float* bias = (const float*)d_in[3];
    float* out = (float*)d_out;
    int P = in_sizes[0] / C_IN;

    char* ws = (char*)d_ws;
    int* idxbuf = (int*)ws;                                    // 4*P ints
    int* cntp   = (int*)(ws + (size_t)4 * P * 4);              // 4 ints (+pad)
    ushort* wbt = (ushort*)(ws + (size_t)4 * P * 4 + 16);      // NFILT*C_OUT*C_IN bf16

    zero_cnt_kernel<<<1, 64, 0, stream>>>(cntp);
    bucketize_kernel<<<(P + 255) / 256, 256, 0, stream>>>(xyz, idxbuf, cntp, P);
    convert_w_kernel<<<(NFILT * C_OUT * C_IN / 8 + 255) / 256, 256, 0, stream>>>(w, wbt);

    dim3 grid(P / BM + NFILT);
    gemm_kernel<<<grid, 256, 0, stream>>>(feat, wbt, bias, idxbuf, cntp, out, P);
}